// Round 1
// baseline (148.430 us; speedup 1.0000x reference)
//
#include <hip/hip_runtime.h>
#include <stdint.h>

typedef __attribute__((ext_vector_type(4))) int int4v;           // 16B LDS frag (fp4 x32)
typedef __attribute__((ext_vector_type(8))) int int8v;           // MFMA f8f6f4 A/B operand
typedef __attribute__((ext_vector_type(4))) float floatx4;       // MFMA C/D
typedef __attribute__((ext_vector_type(16))) unsigned char uchar16;

#define MDIM 8192
#define KDIM 2048
#define NDIM 2048
#define BM 256
#define BN 256
#define KB 1024      // bytes per packed fp4 row (K/2)
#define BKB 128      // staged bytes per row per tile = 256 fp4 k-elements
#define NT 8         // KB / BKB

// async global->LDS, 16B per lane. LDS dest = wave-uniform base + lane*16.
__device__ __forceinline__ void load16_lds(const void* g, void* l) {
  __builtin_amdgcn_global_load_lds(
      (const __attribute__((address_space(1))) void*)g,
      (__attribute__((address_space(3))) void*)l, 16, 0, 0);
}

// ---- Phase 1 (fused): binarize X -> fp4 [M][K/2]; binarize+transpose W -> fp4 [N][K/2] ----
// fp4 e2m1: +1 = 0x2, -1 = 0xA. Low nibble = even k (A and B packed identically,
// so any within-k permutation cancels in the dot product).
#define XBLK 2048   // M*K / (256*32)
#define WBLK 512    // N*K / (256*32)

__global__ void binarize_fused(const float* __restrict__ X,
                               const float* __restrict__ W,
                               unsigned char* __restrict__ Xb,
                               unsigned char* __restrict__ WbT) {
  const int b = blockIdx.x;
  if (b < XBLK) {
    size_t i = ((size_t)b * 256 + threadIdx.x) * 32;   // element index, 32/thread
    const float4* xp = (const float4*)(X + i);
    uchar16 o;
#pragma unroll
    for (int h = 0; h < 8; ++h) {
      float4 a = xp[h];
      unsigned n0 = (a.x < 0.f) ? 0xAu : 0x2u;
      unsigned n1 = (a.y < 0.f) ? 0xAu : 0x2u;
      unsigned n2 = (a.z < 0.f) ? 0xAu : 0x2u;
      unsigned n3 = (a.w < 0.f) ? 0xAu : 0x2u;
      o[2 * h]     = (unsigned char)(n0 | (n1 << 4));
      o[2 * h + 1] = (unsigned char)(n2 | (n3 << 4));
    }
    *(uchar16*)(Xb + i / 2) = o;
  } else {
    const int bw = b - XBLK;
    const int nb = bw & 31;                       // n-block (64 wide)
    const int kb = bw >> 5;                       // 0..15
    const int nn = threadIdx.x & 63;              // lane -> consecutive n (coalesced reads)
    const int kc = kb * 4 + (threadIdx.x >> 6);   // 32-k chunk id, 0..63
    const float* wp = W + (size_t)(kc * 32) * NDIM + nb * 64 + nn;
    uchar16 o;
#pragma unroll
    for (int j = 0; j < 16; ++j) {
      unsigned lo = (wp[(size_t)(2 * j) * NDIM] < 0.f) ? 0xAu : 0x2u;
      unsigned hi = (wp[(size_t)(2 * j + 1) * NDIM] < 0.f) ? 0xAu : 0x2u;
      o[j] = (unsigned char)(lo | (hi << 4));
    }
    *(uchar16*)(WbT + (size_t)(nb * 64 + nn) * KB + kc * 16) = o;
  }
}

// ---- Phase 2: MX-fp4 MFMA GEMM, 256x256 tile, 8 waves (wave tile 128x64),
// double-buffered LDS with counted-vmcnt prefetch (T3/T4-lite). Same XOR-swizzled
// LDS chunk layout that measured zero bank conflicts (row stride 128B, 8-chunk XOR).
// C = A * B^T + bias, exact: fp4 {+1,-1} inputs, fp32 accumulation of ints <= 2048.
__global__ __launch_bounds__(512, 2) void gemm_bin_fp4(
    const unsigned char* __restrict__ A,    // Xb  [M][K/2] fp4
    const unsigned char* __restrict__ B,    // WbT [N][K/2] fp4
    const float* __restrict__ bias,         // [N]
    float* __restrict__ C) {                // [M][N] fp32
  __shared__ __align__(16) unsigned char As[2][BM * BKB];  // 2 x 32 KB
  __shared__ __align__(16) unsigned char Bs[2][BN * BKB];  // 2 x 32 KB

  const int tid = threadIdx.x;
  const int lane = tid & 63;
  const int wv = tid >> 6;     // wave 0..7
  const int wm = wv >> 2;      // wave row half (128 rows)
  const int wn = wv & 3;       // wave col quarter (64 cols)
  const int r = lane & 15;     // MFMA m/n index
  const int q = lane >> 4;     // MFMA quad (k-block select)

  const int m0 = blockIdx.x * BM;
  const int n0 = blockIdx.y * BN;

  floatx4 acc[8][4] = {};

  // staging: 2048 16B-chunks per 32KB tile, 256 per wave (4 rounds of 64 lanes)
  const int qbase = wv * 256;
  int srcoff[4];
#pragma unroll
  for (int i = 0; i < 4; ++i) {
    const int s = qbase + i * 64 + lane;
    const int row = s >> 3;
    const int cg = (s & 7) ^ (row & 7);   // global 16B chunk for this (linear) LDS slot
    srcoff[i] = row * KB + cg * 16;       // bytes
  }
  const unsigned char* Ab = A + (size_t)m0 * KB;
  const unsigned char* Bb = B + (size_t)n0 * KB;

  // prologue: stage tile 0 into buffer 0 (8 loads/thread outstanding)
#pragma unroll
  for (int i = 0; i < 4; ++i) {
    load16_lds(Ab + srcoff[i], &As[0][(qbase + i * 64) * 16]);
    load16_lds(Bb + srcoff[i], &Bs[0][(qbase + i * 64) * 16]);
  }

  for (int t = 0; t < NT; ++t) {
    const int cur = t & 1;
    if (t < NT - 1) {
      // prefetch next tile into the other buffer; keep it in flight across compute
      const int kbb = (t + 1) * BKB;
#pragma unroll
      for (int i = 0; i < 4; ++i) {
        load16_lds(Ab + kbb + srcoff[i], &As[cur ^ 1][(qbase + i * 64) * 16]);
        load16_lds(Bb + kbb + srcoff[i], &Bs[cur ^ 1][(qbase + i * 64) * 16]);
      }
      // 16 outstanding; wait until <=8 -> current tile's 8 loads have landed.
      asm volatile("s_waitcnt vmcnt(8)" ::: "memory");
    } else {
      asm volatile("s_waitcnt vmcnt(0)" ::: "memory");
    }
    __builtin_amdgcn_s_barrier();  // all waves' current-tile loads are in LDS

#pragma unroll
    for (int s2 = 0; s2 < 2; ++s2) {  // two k=128 substeps of the 256-k tile
      int8v b8[4];
#pragma unroll
      for (int tn = 0; tn < 4; ++tn) {
        const int brow = wn * 64 + tn * 16 + r;
        int4v bv = *(const int4v*)(&Bs[cur][brow * BKB + (((s2 * 4 + q) ^ (r & 7)) * 16)]);
        b8[tn] = int8v{bv[0], bv[1], bv[2], bv[3], 0, 0, 0, 0};
      }
#pragma unroll
      for (int tm = 0; tm < 8; ++tm) {
        const int arow = wm * 128 + tm * 16 + r;
        int4v av = *(const int4v*)(&As[cur][arow * BKB + (((s2 * 4 + q) ^ (r & 7)) * 16)]);
        int8v a8 = int8v{av[0], av[1], av[2], av[3], 0, 0, 0, 0};
#pragma unroll
        for (int tn = 0; tn < 4; ++tn)
          // cbsz=4 (A fmt fp4 e2m1), blgp=4 (B fmt fp4); scales = E8M0 127 -> 1.0
          acc[tm][tn] = __builtin_amdgcn_mfma_scale_f32_16x16x128_f8f6f4(
              a8, b8[tn], acc[tm][tn], 4, 4,
              0, 0x7F7F7F7F, 0, 0x7F7F7F7F);
      }
    }
    // ds_reads of buf[cur] all retired (cheap: they were consumed by MFMAs);
    // barrier so next iteration may overwrite buf[cur]. NO vmcnt drain here.
    asm volatile("s_waitcnt lgkmcnt(0)" ::: "memory");
    __builtin_amdgcn_s_barrier();
  }

  // epilogue: C/D layout col=lane&15, row=q*4+v (shape-determined, m121-128)
#pragma unroll
  for (int tn = 0; tn < 4; ++tn) {
    const int col = n0 + wn * 64 + tn * 16 + r;
    const float bv = bias[col];
#pragma unroll
    for (int tm = 0; tm < 8; ++tm) {
      const int rowb = m0 + wm * 128 + tm * 16 + q * 4;
#pragma unroll
      for (int v = 0; v < 4; ++v)
        C[(size_t)(rowb + v) * NDIM + col] = acc[tm][tn][v] + bv;
    }
  }
}

extern "C" void kernel_launch(void* const* d_in, const int* in_sizes, int n_in,
                              void* d_out, int out_size, void* d_ws, size_t ws_size,
                              hipStream_t stream) {
  const float* X = (const float*)d_in[0];     // [8192, 2048]
  const float* W = (const float*)d_in[1];     // [2048, 2048]
  const float* bias = (const float*)d_in[2];  // [2048]
  float* out = (float*)d_out;

  unsigned char* Xb = (unsigned char*)d_ws;                 // 8 MB (fp4 packed)
  unsigned char* WbT = Xb + (size_t)MDIM * KDIM / 2;        // 2 MB (ws 10 MB)

  binarize_fused<<<dim3(XBLK + WBLK), 256, 0, stream>>>(X, W, Xb, WbT);
  gemm_bin_fp4<<<dim3(MDIM / BM, NDIM / BN), 512, 0, stream>>>(Xb, WbT, bias, out);
}

// Round 3
// 143.798 us; speedup vs baseline: 1.0322x; 1.0322x over previous
//
#include <hip/hip_runtime.h>
#include <stdint.h>

typedef __attribute__((ext_vector_type(4))) int int4v;           // 16B LDS frag (fp4 x32)
typedef __attribute__((ext_vector_type(8))) int int8v;           // MFMA f8f6f4 A/B operand
typedef __attribute__((ext_vector_type(4))) float floatx4;       // MFMA C/D
typedef __attribute__((ext_vector_type(16))) unsigned char uchar16;

#define MDIM 8192
#define KDIM 2048
#define NDIM 2048
#define BM 256
#define BN 256
#define KB 1024      // bytes per packed fp4 row (K/2)
#define BKB 128      // staged bytes per row per tile = 256 fp4 k-elements
#define NT 8         // KB / BKB

// async global->LDS, 16B per lane. LDS dest = wave-uniform base + lane*16.
__device__ __forceinline__ void load16_lds(const void* g, void* l) {
  __builtin_amdgcn_global_load_lds(
      (const __attribute__((address_space(1))) void*)g,
      (__attribute__((address_space(3))) void*)l, 16, 0, 0);
}

// ---- Phase 1 (fused): binarize X -> fp4 [M][K/2]; binarize+transpose W -> fp4 [N][K/2] ----
// fp4 e2m1: +1 = 0x2, -1 = 0xA. Low nibble = even k (A and B packed identically,
// so any within-k permutation cancels in the dot product).
#define XBLK 2048   // M*K / (256*32)
#define WBLK 512    // N*K / (256*32)

__global__ void binarize_fused(const float* __restrict__ X,
                               const float* __restrict__ W,
                               unsigned char* __restrict__ Xb,
                               unsigned char* __restrict__ WbT) {
  const int b = blockIdx.x;
  if (b < XBLK) {
    size_t i = ((size_t)b * 256 + threadIdx.x) * 32;   // element index, 32/thread
    const float4* xp = (const float4*)(X + i);
    uchar16 o;
#pragma unroll
    for (int h = 0; h < 8; ++h) {
      float4 a = xp[h];
      unsigned n0 = (a.x < 0.f) ? 0xAu : 0x2u;
      unsigned n1 = (a.y < 0.f) ? 0xAu : 0x2u;
      unsigned n2 = (a.z < 0.f) ? 0xAu : 0x2u;
      unsigned n3 = (a.w < 0.f) ? 0xAu : 0x2u;
      o[2 * h]     = (unsigned char)(n0 | (n1 << 4));
      o[2 * h + 1] = (unsigned char)(n2 | (n3 << 4));
    }
    *(uchar16*)(Xb + i / 2) = o;
  } else {
    const int bw = b - XBLK;
    const int nb = bw & 31;                       // n-block (64 wide)
    const int kb = bw >> 5;                       // 0..15
    const int nn = threadIdx.x & 63;              // lane -> consecutive n (coalesced reads)
    const int kc = kb * 4 + (threadIdx.x >> 6);   // 32-k chunk id, 0..63
    const float* wp = W + (size_t)(kc * 32) * NDIM + nb * 64 + nn;
    uchar16 o;
#pragma unroll
    for (int j = 0; j < 16; ++j) {
      unsigned lo = (wp[(size_t)(2 * j) * NDIM] < 0.f) ? 0xAu : 0x2u;
      unsigned hi = (wp[(size_t)(2 * j + 1) * NDIM] < 0.f) ? 0xAu : 0x2u;
      o[j] = (unsigned char)(lo | (hi << 4));
    }
    *(uchar16*)(WbT + (size_t)(nb * 64 + nn) * KB + kc * 16) = o;
  }
}

// ---- Phase 2: MX-fp4 MFMA GEMM, 256x256 tile, 8 waves (wave tile 128x64),
// double-buffered LDS with counted-vmcnt prefetch (main loop identical to the
// R1 variant that passed with absmax 0). Epilogue: per-wave LDS transpose slab
// with EXPLICIT lgkmcnt fences (the R2 failure was a ds_write->ds_read race:
// TBAA let the compiler skip the wait). 32 float4 stores/thread, 256B segments.
__global__ __launch_bounds__(512, 2) void gemm_bin_fp4(
    const unsigned char* __restrict__ A,    // Xb  [M][K/2] fp4
    const unsigned char* __restrict__ B,    // WbT [N][K/2] fp4
    const float* __restrict__ bias,         // [N]
    float* __restrict__ C) {                // [M][N] fp32
  __shared__ __align__(16) unsigned char As[2][BM * BKB];  // 2 x 32 KB
  __shared__ __align__(16) unsigned char Bs[2][BN * BKB];  // 2 x 32 KB

  const int tid = threadIdx.x;
  const int lane = tid & 63;
  const int wv = tid >> 6;     // wave 0..7
  const int wm = wv >> 2;      // wave row half (128 rows)
  const int wn = wv & 3;       // wave col quarter (64 cols)
  const int r = lane & 15;     // MFMA m/n index
  const int q = lane >> 4;     // MFMA quad (k-block select)

  const int m0 = blockIdx.x * BM;
  const int n0 = blockIdx.y * BN;

  floatx4 acc[8][4] = {};

  // staging: 2048 16B-chunks per 32KB tile, 256 per wave (4 rounds of 64 lanes)
  const int qbase = wv * 256;
  int srcoff[4];
#pragma unroll
  for (int i = 0; i < 4; ++i) {
    const int s = qbase + i * 64 + lane;
    const int row = s >> 3;
    const int cg = (s & 7) ^ (row & 7);   // global 16B chunk for this (linear) LDS slot
    srcoff[i] = row * KB + cg * 16;       // bytes
  }
  const unsigned char* Ab = A + (size_t)m0 * KB;
  const unsigned char* Bb = B + (size_t)n0 * KB;

  // prologue: stage tile 0 into buffer 0 (8 loads/thread outstanding)
#pragma unroll
  for (int i = 0; i < 4; ++i) {
    load16_lds(Ab + srcoff[i], &As[0][(qbase + i * 64) * 16]);
    load16_lds(Bb + srcoff[i], &Bs[0][(qbase + i * 64) * 16]);
  }

  for (int t = 0; t < NT; ++t) {
    const int cur = t & 1;
    if (t < NT - 1) {
      // prefetch next tile into the other buffer; keep it in flight across compute
      const int kbb = (t + 1) * BKB;
#pragma unroll
      for (int i = 0; i < 4; ++i) {
        load16_lds(Ab + kbb + srcoff[i], &As[cur ^ 1][(qbase + i * 64) * 16]);
        load16_lds(Bb + kbb + srcoff[i], &Bs[cur ^ 1][(qbase + i * 64) * 16]);
      }
      // 16 outstanding; wait until <=8 -> current tile's 8 loads have landed.
      asm volatile("s_waitcnt vmcnt(8)" ::: "memory");
    } else {
      asm volatile("s_waitcnt vmcnt(0)" ::: "memory");
    }
    __builtin_amdgcn_s_barrier();  // all waves' current-tile loads are in LDS

#pragma unroll
    for (int s2 = 0; s2 < 2; ++s2) {  // two k=128 substeps of the 256-k tile
      int8v b8[4];
#pragma unroll
      for (int tn = 0; tn < 4; ++tn) {
        const int brow = wn * 64 + tn * 16 + r;
        int4v bv = *(const int4v*)(&Bs[cur][brow * BKB + (((s2 * 4 + q) ^ (r & 7)) * 16)]);
        b8[tn] = int8v{bv[0], bv[1], bv[2], bv[3], 0, 0, 0, 0};
      }
#pragma unroll
      for (int tm = 0; tm < 8; ++tm) {
        const int arow = wm * 128 + tm * 16 + r;
        int4v av = *(const int4v*)(&As[cur][arow * BKB + (((s2 * 4 + q) ^ (r & 7)) * 16)]);
        int8v a8 = int8v{av[0], av[1], av[2], av[3], 0, 0, 0, 0};
#pragma unroll
        for (int tn = 0; tn < 4; ++tn)
          // cbsz=4 (A fmt fp4 e2m1), blgp=4 (B fmt fp4); scales = E8M0 127 -> 1.0
          acc[tm][tn] = __builtin_amdgcn_mfma_scale_f32_16x16x128_f8f6f4(
              a8, b8[tn], acc[tm][tn], 4, 4,
              0, 0x7F7F7F7F, 0, 0x7F7F7F7F);
      }
    }
    // ds_reads of buf[cur] all retired; barrier so next iteration may overwrite
    // buf[cur]. NO vmcnt drain here.
    asm volatile("s_waitcnt lgkmcnt(0)" ::: "memory");
    __builtin_amdgcn_s_barrier();
  }

  // ---- epilogue: vectorized C-write via per-wave LDS transpose slab ----
  // MFMA C/D layout: col=lane&15, row=q*4+v (shape-determined, m121-128).
  // Each wave owns a 4KB slab (16 rows x 64 cols fp32) inside As (32KB = 8x4KB).
  // Explicit fences order the slab write->read alternation (R2 raced without).
  __syncthreads();  // all waves done with MFMA LDS reads; safe to reuse As
  float* slab = (float*)(&As[0][0]) + wv * 1024;

  float bv[4];
#pragma unroll
  for (int tn = 0; tn < 4; ++tn) bv[tn] = bias[n0 + wn * 64 + tn * 16 + r];

  const int lrow = lane >> 4;   // 0..3  (row within 4-row store group)
  const int lc4 = lane & 15;    // float4 column 0..15 (16 lanes = 256B contiguous)

#pragma unroll
  for (int tm = 0; tm < 8; ++tm) {
    // scatter fragment group (bias added) into slab — wave-private
#pragma unroll
    for (int tn = 0; tn < 4; ++tn)
#pragma unroll
      for (int v = 0; v < 4; ++v)
        slab[(q * 4 + v) * 64 + tn * 16 + r] = acc[tm][tn][v] + bv[tn];
    // RAW fence: slab writes must land before the transpose readback
    asm volatile("s_waitcnt lgkmcnt(0)" ::: "memory");
    __builtin_amdgcn_sched_barrier(0);
    // read back row-major as float4, store 4 rows x 256B contiguous per instr
#pragma unroll
    for (int j = 0; j < 4; ++j) {
      const int row = j * 4 + lrow;
      floatx4 val = *(const floatx4*)(&slab[row * 64 + lc4 * 4]);
      *(floatx4*)(&C[(size_t)(m0 + wm * 128 + tm * 16 + row) * NDIM +
                     n0 + wn * 64 + lc4 * 4]) = val;
    }
    // WAR fence: readback must retire before next iteration overwrites slab
    asm volatile("s_waitcnt lgkmcnt(0)" ::: "memory");
    __builtin_amdgcn_sched_barrier(0);
  }
}

extern "C" void kernel_launch(void* const* d_in, const int* in_sizes, int n_in,
                              void* d_out, int out_size, void* d_ws, size_t ws_size,
                              hipStream_t stream) {
  const float* X = (const float*)d_in[0];     // [8192, 2048]
  const float* W = (const float*)d_in[1];     // [2048, 2048]
  const float* bias = (const float*)d_in[2];  // [2048]
  float* out = (float*)d_out;

  unsigned char* Xb = (unsigned char*)d_ws;                 // 8 MB (fp4 packed)
  unsigned char* WbT = Xb + (size_t)MDIM * KDIM / 2;        // 2 MB (ws 10 MB)

  binarize_fused<<<dim3(XBLK + WBLK), 256, 0, stream>>>(X, W, Xb, WbT);
  gemm_bin_fp4<<<dim3(MDIM / BM, NDIM / BN), 512, 0, stream>>>(Xb, WbT, bias, out);
}